// Round 6
// baseline (219.778 us; speedup 1.0000x reference)
//
#include <hip/hip_runtime.h>
#include <hip/hip_bf16.h>

// b=16, n=m=2048, d=dv=128, fp32 in/out, temp=sqrt(128).
// Prep (R5-verified): Q,K,V -> bf16 fragment-tiled:
//   Qg/Kg[b][t128][cc=d/8][m128][8]  (Q pre-scaled by log2e/temp)
//   Vg[b][t128][mcc=m/8][dv][8]      (transposed)
// Attention: St = K.Q^T (32x32x16 bf16 MFMA). K-tile staged in LDS
// (stride 130 ushorts: +1 bank/row -> conflict-free reads & writes);
// V-frags direct from L2 (R5 layout, issued early); P via exp2 + 4x
// shfl_xor(32) register transform (R2/R5-verified). O^T = Vt.P in AGPRs.
// Block 512 = 8 waves (2 q-groups x 4 m-waves), BQ=128, BK=128.
// Grid (16 b, 16 qb) = 256 blocks -> 1 block/CU, 2 waves/SIMD.
// blockIdx.x=b -> 2 batches/XCD: K/V L2 working set 2 MB < 4 MB/XCD.

#define BATCH 16
#define SEQ   2048
#define DIM   128

typedef short bf16x8 __attribute__((ext_vector_type(8)));
typedef float f32x16 __attribute__((ext_vector_type(16)));

static __device__ inline unsigned pk2(float lo, float hi) {
  union { float f; unsigned u; } a, b;
  a.f = lo; b.f = hi;
  return ((b.u + 0x8000u) & 0xffff0000u) | ((a.u + 0x8000u) >> 16);
}
static __device__ inline float fast_exp2(float x) {
#if __has_builtin(__builtin_amdgcn_exp2f)
  return __builtin_amdgcn_exp2f(x);
#else
  return exp2f(x);
#endif
}

// ---- prep (verbatim from R5, verified): fp32 -> bf16 fragment-tiled ----
__global__ __launch_bounds__(256)
void prep_kernel(const float* __restrict__ Q, const float* __restrict__ K,
                 const float* __restrict__ V,
                 unsigned short* __restrict__ Qg, unsigned short* __restrict__ Kg,
                 unsigned short* __restrict__ Vg, float qscale) {
  const int bx = blockIdx.x, tid = threadIdx.x;
  if (bx < 512) {
    const int isQ = (bx >= 256);
    const int t = bx & 255, b = t >> 4, mt = t & 15;
    const float sc = isQ ? qscale : 1.0f;
    const float* src = (isQ ? Q : K) + ((size_t)(b * SEQ) + mt * 128) * DIM;
    unsigned short* dst = (isQ ? Qg : Kg) + (size_t)t * 16384;
#pragma unroll
    for (int i = 0; i < 8; ++i) {
      int idx = i * 256 + tid;
      int cc = idx >> 7, m = idx & 127;
      const float* p = src + (size_t)m * DIM + cc * 8;
      float4 x = *(const float4*)p, y = *(const float4*)(p + 4);
      uint4 o;
      o.x = pk2(x.x * sc, x.y * sc); o.y = pk2(x.z * sc, x.w * sc);
      o.z = pk2(y.x * sc, y.y * sc); o.w = pk2(y.z * sc, y.w * sc);
      *(uint4*)(dst + (size_t)cc * 1024 + m * 8) = o;
    }
  } else {
    __shared__ float tile[128][33];
    const int vb = bx - 512;
    const int b = vb >> 6, r = vb & 63;
    const int mt = r & 15, d0 = (r >> 4) * 32;
    const int c = tid & 7, mr = tid >> 3;
    const float* src = V + ((size_t)(b * SEQ) + mt * 128) * DIM + d0;
#pragma unroll
    for (int it = 0; it < 4; ++it) {
      int m = it * 32 + mr;
      float4 x = *(const float4*)(src + (size_t)m * DIM + c * 4);
      tile[m][c * 4 + 0] = x.x; tile[m][c * 4 + 1] = x.y;
      tile[m][c * 4 + 2] = x.z; tile[m][c * 4 + 3] = x.w;
    }
    __syncthreads();
    const int s = tid >> 5, dr = tid & 31;
    unsigned short* dst = Vg + (size_t)(b * 16 + mt) * 16384;
#pragma unroll
    for (int it = 0; it < 2; ++it) {
      int mcc = it * 8 + s;
      uint4 o;
      o.x = pk2(tile[mcc * 8 + 0][dr], tile[mcc * 8 + 1][dr]);
      o.y = pk2(tile[mcc * 8 + 2][dr], tile[mcc * 8 + 3][dr]);
      o.z = pk2(tile[mcc * 8 + 4][dr], tile[mcc * 8 + 5][dr]);
      o.w = pk2(tile[mcc * 8 + 6][dr], tile[mcc * 8 + 7][dr]);
      *(uint4*)(dst + (size_t)mcc * 1024 + (d0 + dr) * 8) = o;
    }
  }
}

// P transform for one 32x32 St tile (R2/R5-verified):
// C-layout (lane=col=q, regs=m-rows) -> two PV B-frags (k=0..15, 16..31).
static __device__ inline void tile_p(const f32x16& s, int q2, float& lsum,
                                     bf16x8& f0o, bf16x8& f1o) {
  float p[16];
#pragma unroll
  for (int i = 0; i < 16; ++i) p[i] = fast_exp2(s[i]);
  lsum += (((p[0]+p[1])+(p[2]+p[3])) + ((p[4]+p[5])+(p[6]+p[7])))
        + (((p[8]+p[9])+(p[10]+p[11])) + ((p[12]+p[13])+(p[14]+p[15])));
  unsigned d0 = pk2(p[0],  p[1]),  d1 = pk2(p[2],  p[3]);
  unsigned d2 = pk2(p[4],  p[5]),  d3 = pk2(p[6],  p[7]);
  unsigned d4 = pk2(p[8],  p[9]),  d5 = pk2(p[10], p[11]);
  unsigned d6 = pk2(p[12], p[13]), d7 = pk2(p[14], p[15]);
  unsigned t0 = (unsigned)__shfl_xor((int)(q2 ? d0 : d2), 32, 64);
  unsigned t1 = (unsigned)__shfl_xor((int)(q2 ? d1 : d3), 32, 64);
  unsigned t2 = (unsigned)__shfl_xor((int)(q2 ? d4 : d6), 32, 64);
  unsigned t3 = (unsigned)__shfl_xor((int)(q2 ? d5 : d7), 32, 64);
  union { unsigned i[4]; bf16x8 v; } f0, f1;
  f0.i[0] = q2 ? t0 : d0;  f0.i[1] = q2 ? t1 : d1;
  f0.i[2] = q2 ? d2 : t0;  f0.i[3] = q2 ? d3 : t1;
  f1.i[0] = q2 ? t2 : d4;  f1.i[1] = q2 ? t3 : d5;
  f1.i[2] = q2 ? d6 : t2;  f1.i[3] = q2 ? d7 : t3;
  f0o = f0.v; f1o = f1.v;
}

#define KSTRIDE 130   // ushorts: 260 B rows = 65 dwords -> +1 bank per row

__global__ __launch_bounds__(512, 2)
void attn_kernel(const unsigned short* __restrict__ Qg,
                 const unsigned short* __restrict__ Kg,
                 const unsigned short* __restrict__ Vg,
                 float* __restrict__ out) {
  // K tile (128 x 130 ushorts = 33280 B) and epilogue buffers share this.
  __shared__ __align__(16) char smem[34048];
  unsigned short* KsU = (unsigned short*)smem;

  const int tid  = threadIdx.x;
  const int wave = tid >> 6;
  const int w_q  = wave & 1;          // q-group (64 rows) of BQ=128
  const int w_m  = wave >> 1;         // m-chunk (32) of the BK=128 tile
  const int lane = tid & 63;
  const int l31  = lane & 31;
  const int q2   = lane >> 5;
  const int b    = blockIdx.x;
  const int qb   = blockIdx.y;
  const int mch  = w_m * 32;

  const unsigned short* kb = Kg + (size_t)b * SEQ * DIM;
  const unsigned short* vb = Vg + (size_t)b * SEQ * DIM;

  // Q B-frags in regs (64 VGPRs): lane (l31,q2) holds
  // Q[qb*128 + w_q*64 + qt*32 + l31][c*16 + q2*8 + j]
  bf16x8 bq[2][8];
  {
    const unsigned short* Qt = Qg + (size_t)(b * 16 + qb) * 16384;
#pragma unroll
    for (int qt = 0; qt < 2; ++qt)
#pragma unroll
      for (int c = 0; c < 8; ++c)
        bq[qt][c] = *(const bf16x8*)(Qt + (size_t)(2 * c + q2) * 1024 +
                                     (w_q * 64 + qt * 32 + l31) * 8);
  }

  f32x16 oacc[4][2];
#pragma unroll
  for (int dvt = 0; dvt < 4; ++dvt)
#pragma unroll
    for (int qt = 0; qt < 2; ++qt)
#pragma unroll
      for (int i = 0; i < 16; ++i) oacc[dvt][qt][i] = 0.0f;
  float lsum[2] = {0.0f, 0.0f};

  // K-stage prefetch regs: 4 x uint4 = 64 B/thread (32 KB tile / 512 thr)
  uint4 kst[4];
#pragma unroll
  for (int i = 0; i < 4; ++i) {
    int idx = i * 512 + tid;                  // [0,2048): cc=idx>>7, m=idx&127
    kst[i] = *(const uint4*)(kb + (size_t)idx * 8);
  }

  for (int t = 0; t < 16; ++t) {
    __syncthreads();                          // prev tile's K reads done
#pragma unroll
    for (int i = 0; i < 4; ++i) {
      int idx = i * 512 + tid, cc = idx >> 7, m = idx & 127;
      *(uint4*)(KsU + m * KSTRIDE + cc * 8) = kst[i];
    }
    __syncthreads();                          // tile visible

    // St = K.Q^T : A = K-frag (LDS, conflict-free), B = Q (regs).
    // Each ak feeds both q-tiles.
    f32x16 s0, s1;
#pragma unroll
    for (int i = 0; i < 16; ++i) { s0[i] = 0.0f; s1[i] = 0.0f; }
#pragma unroll
    for (int c = 0; c < 8; ++c) {
      bf16x8 ak = *(const bf16x8*)(KsU + (mch + l31) * KSTRIDE + (2 * c + q2) * 8);
      s0 = __builtin_amdgcn_mfma_f32_32x32x16_bf16(ak, bq[0][c], s0, 0, 0, 0);
      s1 = __builtin_amdgcn_mfma_f32_32x32x16_bf16(ak, bq[1][c], s1, 0, 0, 0);
    }

    // K-stage loads for t+1: in flight through exp + PV (latency hidden)
    if (t + 1 < 16) {
      const unsigned short* kn = kb + (size_t)(t + 1) * 16384;
#pragma unroll
      for (int i = 0; i < 4; ++i) {
        int idx = i * 512 + tid;
        kst[i] = *(const uint4*)(kn + (size_t)idx * 8);
      }
    }

    const unsigned short* Vt = vb + (size_t)t * 16384;
    // V A-frags for k-chunk 0 from L2 (issued before exp: latency overlap)
    bf16x8 av0[4];
#pragma unroll
    for (int dvt = 0; dvt < 4; ++dvt)
      av0[dvt] = *(const bf16x8*)(Vt + (size_t)(w_m * 4 + q2) * 1024 +
                                  (dvt * 32 + l31) * 8);

    bf16x8 pf00, pf01, pf10, pf11;
    tile_p(s0, q2, lsum[0], pf00, pf01);
    tile_p(s1, q2, lsum[1], pf10, pf11);

#pragma unroll
    for (int dvt = 0; dvt < 4; ++dvt) {
      oacc[dvt][0] = __builtin_amdgcn_mfma_f32_32x32x16_bf16(av0[dvt], pf00, oacc[dvt][0], 0, 0, 0);
      oacc[dvt][1] = __builtin_amdgcn_mfma_f32_32x32x16_bf16(av0[dvt], pf10, oacc[dvt][1], 0, 0, 0);
    }
    bf16x8 av1[4];
#pragma unroll
    for (int dvt = 0; dvt < 4; ++dvt)
      av1[dvt] = *(const bf16x8*)(Vt + (size_t)(w_m * 4 + 2 + q2) * 1024 +
                                  (dvt * 32 + l31) * 8);
#pragma unroll
    for (int dvt = 0; dvt < 4; ++dvt) {
      oacc[dvt][0] = __builtin_amdgcn_mfma_f32_32x32x16_bf16(av1[dvt], pf01, oacc[dvt][0], 0, 0, 0);
      oacc[dvt][1] = __builtin_amdgcn_mfma_f32_32x32x16_bf16(av1[dvt], pf11, oacc[dvt][1], 0, 0, 0);
    }
  }

  // combine q2-halves of lsum (complementary m-rows, same q-column)
  lsum[0] += __shfl_xor(lsum[0], 32, 64);
  lsum[1] += __shfl_xor(lsum[1], 32, 64);

  // ---- epilogue (R5-verified pattern, per q-group): 4-way m-combine +
  // transpose via LDS, then coalesced float4 stores by all 512 threads.
  __syncthreads();                            // all K-tile reads done
  float* Ob = (float*)smem;                   // [64 q][129] = 33024 B
  float* Ls = (float*)(smem + 33024);         // [4 w_m][64 q] = 1024 B

  for (int g = 0; g < 2; ++g) {
#pragma unroll
    for (int ph = 0; ph < 4; ++ph) {
      if (w_q == g && w_m == ph) {
#pragma unroll
        for (int qt = 0; qt < 2; ++qt) {
#pragma unroll
          for (int dvt = 0; dvt < 4; ++dvt) {
#pragma unroll
            for (int r = 0; r < 16; ++r) {
              int q  = qt * 32 + l31;
              int dv = dvt * 32 + (r & 3) + 8 * (r >> 2) + 4 * q2;
              float v = oacc[dvt][qt][r];
              if (ph) v += Ob[q * 129 + dv];
              Ob[q * 129 + dv] = v;
            }
          }
          if (q2 == 0) Ls[w_m * 64 + qt * 32 + l31] = lsum[qt];
        }
      }
      __syncthreads();
    }
    float* ob = out + ((size_t)(b * SEQ) + qb * 128 + g * 64) * DIM;
#pragma unroll
    for (int j = 0; j < 4; ++j) {
      int fid = j * 512 + tid;
      int q = fid >> 5, dvi = fid & 31;
      float linv = 1.0f / (Ls[q] + Ls[64 + q] + Ls[128 + q] + Ls[192 + q]);
      float4 o;
      o.x = Ob[q * 129 + dvi * 4 + 0] * linv;
      o.y = Ob[q * 129 + dvi * 4 + 1] * linv;
      o.z = Ob[q * 129 + dvi * 4 + 2] * linv;
      o.w = Ob[q * 129 + dvi * 4 + 3] * linv;
      *(float4*)(ob + (size_t)q * DIM + dvi * 4) = o;
    }
    __syncthreads();                          // Ob reused by next group
  }
}

extern "C" void kernel_launch(void* const* d_in, const int* in_sizes, int n_in,
                              void* d_out, int out_size, void* d_ws, size_t ws_size,
                              hipStream_t stream) {
  const float* Q = (const float*)d_in[0];
  const float* K = (const float*)d_in[1];
  const float* V = (const float*)d_in[2];
  float* out = (float*)d_out;

  const size_t elems = (size_t)BATCH * SEQ * DIM;   // 4,194,304
  unsigned short* Qg = (unsigned short*)d_ws;       // 8 MB
  unsigned short* Kg = Qg + elems;                  // 8 MB
  unsigned short* Vg = Kg + elems;                  // 8 MB (ws >= 24 MB)

  const double TEMPERATURE = 11.313708498984761;
  const float qscale = (float)(1.4426950408889634 / TEMPERATURE);  // log2(e)/temp

  prep_kernel<<<1536, 256, 0, stream>>>(Q, K, V, Qg, Kg, Vg, qscale);
  attn_kernel<<<dim3(BATCH, SEQ / 128), 512, 0, stream>>>(Qg, Kg, Vg, out);
}

// Round 8
// 167.541 us; speedup vs baseline: 1.3118x; 1.3118x over previous
//
#include <hip/hip_runtime.h>
#include <hip/hip_bf16.h>

// b=16, n=m=2048, d=dv=128, fp32 in/out, temp=sqrt(128).
// Prep (R5-verified): Q,K,V -> bf16 fragment-tiled:
//   Qg/Kg[b][t128][cc=d/8][m128][8]  (Q pre-scaled by log2e/temp)
//   Vg[b][t128][mcc=m/8][dv][8]      (transposed)
// Attention: St = K.Q^T (32x32x16 bf16 MFMA). K staged to LDS via
// __builtin_amdgcn_global_load_lds width=16, double-buffered 2x32KB.
// R7 RACE FIX: explicit s_waitcnt vmcnt(0) before each top-of-loop
// __syncthreads() — the compiler does NOT reliably drain in-flight
// global_load_lds DMA at a barrier reached via the loop back-edge, so
// other waves could read a buffer before the DMA landed (first launch
// passed, graph replays diverged). The drain is the intended pipeline
// semantic anyway (staging for tile t completes at the barrier that
// opens iteration t); V loads of the prior iteration are already consumed.
// V-frags direct from L2 (R5-verified). P = exp2(St) via 4x shfl_xor(32)
// register transform (R2/R5-verified). O^T = Vt.P in AGPRs.
// Block 512 = 8 waves (2 q-groups x 4 m-waves), BQ=128, BK=128.
// Grid (16 b, 16 qb) -> XCD = b%8: 2 batches/XCD, K+V 2 MB < 4 MB L2/XCD.

#define BATCH 16
#define SEQ   2048
#define DIM   128

typedef short bf16x8 __attribute__((ext_vector_type(8)));
typedef float f32x16 __attribute__((ext_vector_type(16)));

static __device__ inline unsigned pk2(float lo, float hi) {
  union { float f; unsigned u; } a, b;
  a.f = lo; b.f = hi;
  return ((b.u + 0x8000u) & 0xffff0000u) | ((a.u + 0x8000u) >> 16);
}
static __device__ inline float fast_exp2(float x) {
#if __has_builtin(__builtin_amdgcn_exp2f)
  return __builtin_amdgcn_exp2f(x);
#else
  return exp2f(x);
#endif
}
// async global->LDS, 16B per lane; lds base wave-uniform, g per-lane.
static __device__ inline void async16(void* lds, const void* g) {
  __builtin_amdgcn_global_load_lds(
      (const __attribute__((address_space(1))) unsigned int*)g,
      (__attribute__((address_space(3))) unsigned int*)lds, 16, 0, 0);
}

// ---- prep (verbatim from R5, verified): fp32 -> bf16 fragment-tiled ----
__global__ __launch_bounds__(256)
void prep_kernel(const float* __restrict__ Q, const float* __restrict__ K,
                 const float* __restrict__ V,
                 unsigned short* __restrict__ Qg, unsigned short* __restrict__ Kg,
                 unsigned short* __restrict__ Vg, float qscale) {
  const int bx = blockIdx.x, tid = threadIdx.x;
  if (bx < 512) {
    const int isQ = (bx >= 256);
    const int t = bx & 255, b = t >> 4, mt = t & 15;
    const float sc = isQ ? qscale : 1.0f;
    const float* src = (isQ ? Q : K) + ((size_t)(b * SEQ) + mt * 128) * DIM;
    unsigned short* dst = (isQ ? Qg : Kg) + (size_t)t * 16384;
#pragma unroll
    for (int i = 0; i < 8; ++i) {
      int idx = i * 256 + tid;
      int cc = idx >> 7, m = idx & 127;
      const float* p = src + (size_t)m * DIM + cc * 8;
      float4 x = *(const float4*)p, y = *(const float4*)(p + 4);
      uint4 o;
      o.x = pk2(x.x * sc, x.y * sc); o.y = pk2(x.z * sc, x.w * sc);
      o.z = pk2(y.x * sc, y.y * sc); o.w = pk2(y.z * sc, y.w * sc);
      *(uint4*)(dst + (size_t)cc * 1024 + m * 8) = o;
    }
  } else {
    __shared__ float tile[128][33];
    const int vb = bx - 512;
    const int b = vb >> 6, r = vb & 63;
    const int mt = r & 15, d0 = (r >> 4) * 32;
    const int c = tid & 7, mr = tid >> 3;
    const float* src = V + ((size_t)(b * SEQ) + mt * 128) * DIM + d0;
#pragma unroll
    for (int it = 0; it < 4; ++it) {
      int m = it * 32 + mr;
      float4 x = *(const float4*)(src + (size_t)m * DIM + c * 4);
      tile[m][c * 4 + 0] = x.x; tile[m][c * 4 + 1] = x.y;
      tile[m][c * 4 + 2] = x.z; tile[m][c * 4 + 3] = x.w;
    }
    __syncthreads();
    const int s = tid >> 5, dr = tid & 31;
    unsigned short* dst = Vg + (size_t)(b * 16 + mt) * 16384;
#pragma unroll
    for (int it = 0; it < 2; ++it) {
      int mcc = it * 8 + s;
      uint4 o;
      o.x = pk2(tile[mcc * 8 + 0][dr], tile[mcc * 8 + 1][dr]);
      o.y = pk2(tile[mcc * 8 + 2][dr], tile[mcc * 8 + 3][dr]);
      o.z = pk2(tile[mcc * 8 + 4][dr], tile[mcc * 8 + 5][dr]);
      o.w = pk2(tile[mcc * 8 + 6][dr], tile[mcc * 8 + 7][dr]);
      *(uint4*)(dst + (size_t)mcc * 1024 + (d0 + dr) * 8) = o;
    }
  }
}

// P transform for one 32x32 St tile (R2/R5-verified):
// C-layout (lane=col=q, regs=m-rows) -> two PV B-frags (k=0..15, 16..31).
static __device__ inline void tile_p(const f32x16& s, int q2, float& lsum,
                                     bf16x8& f0o, bf16x8& f1o) {
  float p[16];
#pragma unroll
  for (int i = 0; i < 16; ++i) p[i] = fast_exp2(s[i]);
  lsum += (((p[0]+p[1])+(p[2]+p[3])) + ((p[4]+p[5])+(p[6]+p[7])))
        + (((p[8]+p[9])+(p[10]+p[11])) + ((p[12]+p[13])+(p[14]+p[15])));
  unsigned d0 = pk2(p[0],  p[1]),  d1 = pk2(p[2],  p[3]);
  unsigned d2 = pk2(p[4],  p[5]),  d3 = pk2(p[6],  p[7]);
  unsigned d4 = pk2(p[8],  p[9]),  d5 = pk2(p[10], p[11]);
  unsigned d6 = pk2(p[12], p[13]), d7 = pk2(p[14], p[15]);
  unsigned t0 = (unsigned)__shfl_xor((int)(q2 ? d0 : d2), 32, 64);
  unsigned t1 = (unsigned)__shfl_xor((int)(q2 ? d1 : d3), 32, 64);
  unsigned t2 = (unsigned)__shfl_xor((int)(q2 ? d4 : d6), 32, 64);
  unsigned t3 = (unsigned)__shfl_xor((int)(q2 ? d5 : d7), 32, 64);
  union { unsigned i[4]; bf16x8 v; } f0, f1;
  f0.i[0] = q2 ? t0 : d0;  f0.i[1] = q2 ? t1 : d1;
  f0.i[2] = q2 ? d2 : t0;  f0.i[3] = q2 ? d3 : t1;
  f1.i[0] = q2 ? t2 : d4;  f1.i[1] = q2 ? t3 : d5;
  f1.i[2] = q2 ? d6 : t2;  f1.i[3] = q2 ? d7 : t3;
  f0o = f0.v; f1o = f1.v;
}

__global__ __launch_bounds__(512, 2)
void attn_kernel(const unsigned short* __restrict__ Qg,
                 const unsigned short* __restrict__ Kg,
                 const unsigned short* __restrict__ Vg,
                 float* __restrict__ out) {
  // Two 32KB K-tile buffers; epilogue (34KB) aliases them after the loop.
  __shared__ __align__(16) char smem[65536];

  const int tid  = threadIdx.x;
  const int wave = tid >> 6;
  const int w_q  = wave & 1;          // q-group (64 rows) of BQ=128
  const int w_m  = wave >> 1;         // m-chunk (32) of the BK=128 tile
  const int lane = tid & 63;
  const int l31  = lane & 31;
  const int q2   = lane >> 5;
  const int b    = blockIdx.x;
  const int qb   = blockIdx.y;
  const int mch  = w_m * 32;

  const unsigned short* kb = Kg + (size_t)b * SEQ * DIM;
  const unsigned short* vb = Vg + (size_t)b * SEQ * DIM;

  // Q B-frags in regs (64 VGPRs)
  bf16x8 bq[2][8];
  {
    const unsigned short* Qt = Qg + (size_t)(b * 16 + qb) * 16384;
#pragma unroll
    for (int qt = 0; qt < 2; ++qt)
#pragma unroll
      for (int c = 0; c < 8; ++c)
        bq[qt][c] = *(const bf16x8*)(Qt + (size_t)(2 * c + q2) * 1024 +
                                     (w_q * 64 + qt * 32 + l31) * 8);
  }

  f32x16 oacc[4][2];
#pragma unroll
  for (int dvt = 0; dvt < 4; ++dvt)
#pragma unroll
    for (int qt = 0; qt < 2; ++qt)
#pragma unroll
      for (int i = 0; i < 16; ++i) oacc[dvt][qt][i] = 0.0f;
  float lsum[2] = {0.0f, 0.0f};

  // prologue: async-stage tile 0 into buffer 0 (each wave copies 4KB)
  {
    const char* g = (const char*)kb + wave * 4096 + lane * 16;
    char* l = smem + wave * 4096;
#pragma unroll
    for (int i = 0; i < 4; ++i) async16(l + i * 1024, g + i * 1024);
  }

  for (int t = 0; t < 16; ++t) {
    const int cur = t & 1;
    // RACE FIX: explicitly drain this wave's in-flight DMA before the
    // barrier — buf[cur]'s staging must be complete (and visible to all
    // waves) when any wave passes. The compiler does not reliably insert
    // this on the back-edge path (R7 replay divergence).
    asm volatile("s_waitcnt vmcnt(0)" ::: "memory");
    __syncthreads();   // buf[cur] staged; prev readers of buf[cur^1] done

    const unsigned short* Vt = vb + (size_t)t * 16384;
    // V A-frags k-chunk 0: issued first (L2 latency overlaps exp below)
    bf16x8 av0[4];
#pragma unroll
    for (int dvt = 0; dvt < 4; ++dvt)
      av0[dvt] = *(const bf16x8*)(Vt + (size_t)(w_m * 4 + q2) * 1024 +
                                  (dvt * 32 + l31) * 8);

    // async-stage tile t+1 into the other buffer (drained at next barrier)
    if (t + 1 < 16) {
      const char* g = (const char*)(kb + (size_t)(t + 1) * 16384) + wave * 4096 + lane * 16;
      char* l = smem + (cur ^ 1) * 32768 + wave * 4096;
#pragma unroll
      for (int i = 0; i < 4; ++i) async16(l + i * 1024, g + i * 1024);
    }

    // St = K.Q^T : A = K-frag from LDS (contiguous b128, conflict-free)
    const unsigned short* KsU = (const unsigned short*)(smem + cur * 32768);
    f32x16 s0, s1;
#pragma unroll
    for (int i = 0; i < 16; ++i) { s0[i] = 0.0f; s1[i] = 0.0f; }
#pragma unroll
    for (int c = 0; c < 8; ++c) {
      bf16x8 ak = *(const bf16x8*)(KsU + (size_t)(2 * c + q2) * 1024 + (mch + l31) * 8);
      s0 = __builtin_amdgcn_mfma_f32_32x32x16_bf16(ak, bq[0][c], s0, 0, 0, 0);
      s1 = __builtin_amdgcn_mfma_f32_32x32x16_bf16(ak, bq[1][c], s1, 0, 0, 0);
    }

    bf16x8 pf00, pf01, pf10, pf11;
    tile_p(s0, q2, lsum[0], pf00, pf01);
    tile_p(s1, q2, lsum[1], pf10, pf11);

#pragma unroll
    for (int dvt = 0; dvt < 4; ++dvt) {
      oacc[dvt][0] = __builtin_amdgcn_mfma_f32_32x32x16_bf16(av0[dvt], pf00, oacc[dvt][0], 0, 0, 0);
      oacc[dvt][1] = __builtin_amdgcn_mfma_f32_32x32x16_bf16(av0[dvt], pf10, oacc[dvt][1], 0, 0, 0);
    }
    bf16x8 av1[4];
#pragma unroll
    for (int dvt = 0; dvt < 4; ++dvt)
      av1[dvt] = *(const bf16x8*)(Vt + (size_t)(w_m * 4 + 2 + q2) * 1024 +
                                  (dvt * 32 + l31) * 8);
#pragma unroll
    for (int dvt = 0; dvt < 4; ++dvt) {
      oacc[dvt][0] = __builtin_amdgcn_mfma_f32_32x32x16_bf16(av1[dvt], pf01, oacc[dvt][0], 0, 0, 0);
      oacc[dvt][1] = __builtin_amdgcn_mfma_f32_32x32x16_bf16(av1[dvt], pf11, oacc[dvt][1], 0, 0, 0);
    }
  }

  // combine q2-halves of lsum (complementary m-rows, same q-column)
  lsum[0] += __shfl_xor(lsum[0], 32, 64);
  lsum[1] += __shfl_xor(lsum[1], 32, 64);

  // ---- epilogue (R5/R6-verified): 4-way m-combine + transpose via LDS ----
  asm volatile("s_waitcnt vmcnt(0)" ::: "memory");  // safety: no DMA in flight
  __syncthreads();                            // all K-tile reads done
  float* Ob = (float*)smem;                   // [64 q][129] = 33024 B
  float* Ls = (float*)(smem + 33024);         // [4 w_m][64 q] = 1024 B

  for (int g = 0; g < 2; ++g) {
#pragma unroll
    for (int ph = 0; ph < 4; ++ph) {
      if (w_q == g && w_m == ph) {
#pragma unroll
        for (int qt = 0; qt < 2; ++qt) {
#pragma unroll
          for (int dvt = 0; dvt < 4; ++dvt) {
#pragma unroll
            for (int r = 0; r < 16; ++r) {
              int q  = qt * 32 + l31;
              int dv = dvt * 32 + (r & 3) + 8 * (r >> 2) + 4 * q2;
              float v = oacc[dvt][qt][r];
              if (ph) v += Ob[q * 129 + dv];
              Ob[q * 129 + dv] = v;
            }
          }
          if (q2 == 0) Ls[w_m * 64 + qt * 32 + l31] = lsum[qt];
        }
      }
      __syncthreads();
    }
    float* ob = out + ((size_t)(b * SEQ) + qb * 128 + g * 64) * DIM;
#pragma unroll
    for (int j = 0; j < 4; ++j) {
      int fid = j * 512 + tid;
      int q = fid >> 5, dvi = fid & 31;
      float linv = 1.0f / (Ls[q] + Ls[64 + q] + Ls[128 + q] + Ls[192 + q]);
      float4 o;
      o.x = Ob[q * 129 + dvi * 4 + 0] * linv;
      o.y = Ob[q * 129 + dvi * 4 + 1] * linv;
      o.z = Ob[q * 129 + dvi * 4 + 2] * linv;
      o.w = Ob[q * 129 + dvi * 4 + 3] * linv;
      *(float4*)(ob + (size_t)q * DIM + dvi * 4) = o;
    }
    __syncthreads();                          // Ob reused by next group
  }
}

extern "C" void kernel_launch(void* const* d_in, const int* in_sizes, int n_in,
                              void* d_out, int out_size, void* d_ws, size_t ws_size,
                              hipStream_t stream) {
  const float* Q = (const float*)d_in[0];
  const float* K = (const float*)d_in[1];
  const float* V = (const float*)d_in[2];
  float* out = (float*)d_out;

  const size_t elems = (size_t)BATCH * SEQ * DIM;   // 4,194,304
  unsigned short* Qg = (unsigned short*)d_ws;       // 8 MB
  unsigned short* Kg = Qg + elems;                  // 8 MB
  unsigned short* Vg = Kg + elems;                  // 8 MB (ws >= 24 MB)

  const double TEMPERATURE = 11.313708498984761;
  const float qscale = (float)(1.4426950408889634 / TEMPERATURE);  // log2(e)/temp

  prep_kernel<<<1536, 256, 0, stream>>>(Q, K, V, Qg, Kg, Vg, qscale);
  attn_kernel<<<dim3(BATCH, SEQ / 128), 512, 0, stream>>>(Qg, Kg, Vg, out);
}